// Round 2
// baseline (967.591 us; speedup 1.0000x reference)
//
#include <hip/hip_runtime.h>

// LSTMNextToken: embed-gather -> 2x LSTM -> LayerNorm -> tied-embedding head.
// I/O dtypes per reference: all float tensors are float32; x is int32.
// Internals use bf16 MFMA where the 2% absmax threshold permits.
//
// Pipeline:
//  k_ew    : EW[v][g] = sum_d embed[v,d]*Wih0[g,d] + bih0[g]+bhh0[g]   (433x480 f32)
//  k_prep2 : bf16 zero-padded copies W1p[480][128], embP[448][128]; b1s=bih1+bhh1 (f32)
//  k_rec<0>: batch-parallel LSTM layer 0 (gate src = EW gather via x) -> hb0 bf16 [M][128]
//  k_xg1   : MFMA GEMM xg = hb0 @ W1p^T + b1s -> bf16 [M][480]
//  k_rec<1>: LSTM layer 1 (gate src = xg) -> h1 f32 [M][120]
//  k_ln    : LayerNorm rows -> h1n bf16 [M][128] (pad zeroed; aliases hb0)
//  k_head  : MFMA GEMM logits = h1n @ embP^T -> d_out f32 [M][433]

#define VSZ 433
#define DIM 120
#define BSZ 4096
#define SEQ 16
#define H4  480
#define MTOT (BSZ*SEQ)   // 65536
#define KP  128          // padded K for MFMA
#define NPAD 448         // padded vocab for head
#define TB  16           // batch rows per rec block
#define KSL 24           // K-slice for Whh staging

typedef unsigned int   u32;
typedef unsigned short u16;
typedef __attribute__((ext_vector_type(8))) short v8bf;  // 8 x bf16 (4 VGPRs)
typedef __attribute__((ext_vector_type(4))) float v4f;   // MFMA acc

__device__ __forceinline__ float bf2f(u16 u){ union{u32 i;float f;}z; z.i=((u32)u)<<16; return z.f; }
__device__ __forceinline__ u16 f2bf(float f){ // RNE
  union{float f;u32 u;}z; z.f=f;
  u32 u = z.u + 0x7fffu + ((z.u>>16)&1u);
  return (u16)(u>>16);
}

// ---------------- workspace layout (bytes, 256-aligned) ----------------
#define EW_OFF   0u          // 433*480*4   = 831360
#define B1S_OFF  831488u     // 480*4       = 1920
#define W1P_OFF  833408u     // 480*128*2   = 122880
#define EMBP_OFF 956288u     // 448*128*2   = 114688
#define HB0_OFF  1070976u    // 65536*128*2 = 16777216
#define XG_OFF   17848192u   // 65536*480*2 = 62914560
#define H1_OFF   80762752u   // 65536*120*4 = 31457280 (end 112220032 ~107 MB)
#define H1N_OFF  HB0_OFF     // alias: hb0 dead after k_xg1

// ---------------- k_ew: EW = embed @ Wih0^T + bih0 + bhh0 ----------------
__global__ __launch_bounds__(512) void k_ew(const float* __restrict__ embed,
                                            const float* __restrict__ Wih0,
                                            const float* __restrict__ bih0,
                                            const float* __restrict__ bhh0,
                                            float* __restrict__ EW)
{
  __shared__ float e[DIM];
  const int v = blockIdx.x, tid = threadIdx.x;
  if (tid < DIM) e[tid] = embed[v*DIM + tid];
  __syncthreads();
  if (tid < H4) {
    float acc = bih0[tid] + bhh0[tid];
    #pragma unroll
    for (int k0 = 0; k0 < DIM; k0 += 4) {
      float4 w = *(const float4*)(Wih0 + tid*DIM + k0);
      acc = fmaf(e[k0+0], w.x, acc);
      acc = fmaf(e[k0+1], w.y, acc);
      acc = fmaf(e[k0+2], w.z, acc);
      acc = fmaf(e[k0+3], w.w, acc);
    }
    EW[v*H4 + tid] = acc;
  }
}

// ---------------- k_prep2: bf16 padded copies + bias sum ----------------
__global__ __launch_bounds__(256) void k_prep2(const float* __restrict__ Wih1,
                                               const float* __restrict__ embed,
                                               const float* __restrict__ bih1,
                                               const float* __restrict__ bhh1,
                                               u16* __restrict__ W1p,
                                               u16* __restrict__ embP,
                                               float* __restrict__ b1s)
{
  const int idx = blockIdx.x*256 + threadIdx.x;
  if (idx < H4*KP) {
    int g = idx >> 7, k = idx & 127;
    W1p[idx] = (k < DIM) ? f2bf(Wih1[g*DIM + k]) : (u16)0;
  } else if (idx < H4*KP + NPAD*KP) {
    int i2 = idx - H4*KP;
    int n = i2 >> 7, k = i2 & 127;
    embP[i2] = (n < VSZ && k < DIM) ? f2bf(embed[n*DIM + k]) : (u16)0;
  } else if (idx < H4*KP + NPAD*KP + H4) {
    int g = idx - (H4*KP + NPAD*KP);
    b1s[g] = bih1[g] + bhh1[g];
  }
}

// ---------------- k_rec: one LSTM layer, batch-parallel, f32 recurrence ----------------
// Block: 512 threads, TB=16 batch rows, loops t=0..15 internally.
// Phase A: gates[16][480] = src + h @ Whh^T (Whh staged f32 in 24-wide K slices in LDS).
// Thread (tx,ty) computes gates for rows b=ty*4+r at dim tx: acc[r][j] = gate j of (b,tx)
// (j=0..3 are exactly i,f,g,o at offsets 0,120,240,360) -> phase B runs from registers.
template<int LAYER>
__global__ __launch_bounds__(512) void k_rec(const float* __restrict__ Whh,
                                             const float* __restrict__ EW,
                                             const int* __restrict__ x,
                                             const u16* __restrict__ xg,
                                             u16* __restrict__ hb0,
                                             float* __restrict__ h1)
{
  __shared__ float hL[TB][DIM];                 //  7680 B
  __shared__ __align__(16) float Ws[H4][KSL];   // 46080 B
  __shared__ int xL[TB*SEQ];                    //  1024 B   (total 54784 B)

  const int tid = threadIdx.x;
  const int b0  = blockIdx.x * TB;
  const int tx  = tid % 120;     // gate dim (phase A & B)
  const int ty  = tid / 120;     // 0..3 active, 4 inactive

  if (LAYER == 0)
    for (int i = tid; i < TB*SEQ; i += 512) xL[i] = x[b0*SEQ + i];
  for (int i = tid; i < TB*DIM; i += 512) (&hL[0][0])[i] = 0.f;

  float C[4] = {0.f, 0.f, 0.f, 0.f};            // c state: row b = ty*4 + r
  __syncthreads();

  for (int t = 0; t < SEQ; ++t) {
    float acc[4][4];
    if (ty < 4) {
      #pragma unroll
      for (int r = 0; r < 4; ++r) {
        const int b = ty*4 + r;
        if (LAYER == 0) {
          const float* row = EW + (size_t)xL[b*SEQ + t] * H4;
          #pragma unroll
          for (int j = 0; j < 4; ++j) acc[r][j] = row[tx + 120*j];
        } else {
          const u16* row = xg + ((size_t)((b0 + b)*SEQ + t)) * H4;
          #pragma unroll
          for (int j = 0; j < 4; ++j) acc[r][j] = bf2f(row[tx + 120*j]);
        }
      }
    }
    // K loop: 5 slices of 24
    for (int s = 0; s < 5; ++s) {
      const int k0 = s * KSL;
      __syncthreads();  // prior slice's Ws reads done before overwrite
      for (int i = tid; i < H4*KSL/4; i += 512) {
        int g = i / 6, q = i % 6;
        *(float4*)&Ws[g][q*4] = *(const float4*)(Whh + g*DIM + k0 + q*4);
      }
      __syncthreads();
      if (ty < 4) {
        #pragma unroll
        for (int kk8 = 0; kk8 < KSL; kk8 += 8) {
          float hv[4][8];
          #pragma unroll
          for (int r = 0; r < 4; ++r) {
            float4 p0 = *(const float4*)&hL[ty*4 + r][k0 + kk8];
            float4 p1 = *(const float4*)&hL[ty*4 + r][k0 + kk8 + 4];
            hv[r][0]=p0.x; hv[r][1]=p0.y; hv[r][2]=p0.z; hv[r][3]=p0.w;
            hv[r][4]=p1.x; hv[r][5]=p1.y; hv[r][6]=p1.z; hv[r][7]=p1.w;
          }
          #pragma unroll
          for (int j = 0; j < 4; ++j) {
            const int g = tx + 120*j;
            float4 w0 = *(const float4*)&Ws[g][kk8];
            float4 w1 = *(const float4*)&Ws[g][kk8 + 4];
            float wf[8] = {w0.x,w0.y,w0.z,w0.w, w1.x,w1.y,w1.z,w1.w};
            #pragma unroll
            for (int r = 0; r < 4; ++r)
              #pragma unroll
              for (int kk = 0; kk < 8; ++kk)
                acc[r][j] = fmaf(hv[r][kk], wf[kk], acc[r][j]);
          }
        }
      }
    }
    __syncthreads();  // all hL reads of this step done before phase-B overwrite
    // Phase B: acc[r][0..3] = i,f,g,o gates (PyTorch order) for row b, dim tx
    if (ty < 4) {
      #pragma unroll
      for (int r = 0; r < 4; ++r) {
        const int b = ty*4 + r;
        const float gi = acc[r][0];
        const float gf = acc[r][1];
        const float gg = acc[r][2];
        const float go = acc[r][3];
        const float si = 1.f / (1.f + __expf(-gi));
        const float sf = 1.f / (1.f + __expf(-gf));
        const float tg = 1.f - 2.f / (__expf(2.f*gg) + 1.f);
        const float so = 1.f / (1.f + __expf(-go));
        const float c  = sf * C[r] + si * tg;
        C[r] = c;
        const float tc = 1.f - 2.f / (__expf(2.f*c) + 1.f);
        const float h  = so * tc;
        hL[b][tx] = h;
        const size_t m = (size_t)(b0 + b)*SEQ + t;
        if (LAYER == 0) hb0[m*KP + tx] = f2bf(h);
        else            h1[m*DIM + tx] = h;
      }
    }
    // next iteration's first __syncthreads() (slice s=0) orders hL writes vs reads
  }
}

// ---------------- k_xg1: MFMA GEMM xg = hb0 @ W1p^T + b1s ----------------
// block = 4 waves; wave handles 4 M-tiles (64 rows/wave, 256 rows/block)
__global__ __launch_bounds__(256) void k_xg1(const u16* __restrict__ A,   // [M][128]
                                             const u16* __restrict__ Wp,  // [480][128]
                                             const float* __restrict__ bsum,
                                             u16* __restrict__ xg)        // [M][480]
{
  const int wv = threadIdx.x >> 6, lane = threadIdx.x & 63;
  const int cl = lane & 15, quad = lane >> 4;
  const int mtb = (blockIdx.x*4 + wv)*4;   // first of 4 m-tiles
  v8bf a[4][4];
  #pragma unroll
  for (int i = 0; i < 4; ++i)
    #pragma unroll
    for (int kt = 0; kt < 4; ++kt)
      a[i][kt] = *(const v8bf*)&A[((size_t)(mtb+i)*16 + cl)*KP + kt*32 + quad*8];
  for (int nt = 0; nt < H4/16; ++nt) {
    const int n = nt*16 + cl;
    v8bf bfr[4];
    #pragma unroll
    for (int kt = 0; kt < 4; ++kt)
      bfr[kt] = *(const v8bf*)&Wp[(size_t)n*KP + kt*32 + quad*8];
    const float bias = bsum[n];
    #pragma unroll
    for (int i = 0; i < 4; ++i) {
      v4f acc = {bias, bias, bias, bias};
      #pragma unroll
      for (int kt = 0; kt < 4; ++kt)
        acc = __builtin_amdgcn_mfma_f32_16x16x32_bf16(a[i][kt], bfr[kt], acc, 0, 0, 0);
      #pragma unroll
      for (int r = 0; r < 4; ++r)
        xg[(size_t)((mtb+i)*16 + quad*4 + r)*H4 + n] = f2bf(acc[r]);
    }
  }
}

// ---------------- k_ln: LayerNorm rows of h1 -> h1n (bf16, padded) ----------------
__global__ __launch_bounds__(256) void k_ln(const float* __restrict__ h1,
                                            const float* __restrict__ gamma,
                                            const float* __restrict__ beta,
                                            u16* __restrict__ h1n)
{
  const int m = blockIdx.x*256 + threadIdx.x;
  const float* row = h1 + (size_t)m*DIM;
  float v[DIM];
  float s = 0.f;
  #pragma unroll
  for (int i = 0; i < DIM/4; ++i) {
    float4 q = *(const float4*)(row + i*4);
    v[i*4+0]=q.x; v[i*4+1]=q.y; v[i*4+2]=q.z; v[i*4+3]=q.w;
    s += q.x + q.y + q.z + q.w;
  }
  const float mu = s * (1.f/DIM);
  float s2 = 0.f;
  #pragma unroll
  for (int i = 0; i < DIM; ++i) { float d = v[i]-mu; s2 = fmaf(d, d, s2); }
  const float rstd = rsqrtf(s2*(1.f/DIM) + 1e-5f);
  u32* dst = (u32*)(h1n + (size_t)m*KP);
  #pragma unroll
  for (int i = 0; i < DIM/2; ++i) {
    u16 lo = f2bf(fmaf((v[2*i  ]-mu)*rstd, gamma[2*i  ], beta[2*i  ]));
    u16 hi = f2bf(fmaf((v[2*i+1]-mu)*rstd, gamma[2*i+1], beta[2*i+1]));
    dst[i] = (u32)lo | ((u32)hi << 16);
  }
  dst[60] = 0u; dst[61] = 0u; dst[62] = 0u; dst[63] = 0u;  // zero pad cols 120..127
}

// ---------------- k_head: MFMA GEMM logits = h1n @ embP^T (f32 out) ----------------
__global__ __launch_bounds__(256) void k_head(const u16* __restrict__ A,   // [M][128]
                                              const u16* __restrict__ Bp,  // [448][128]
                                              float* __restrict__ out)     // [M][433]
{
  const int wv = threadIdx.x >> 6, lane = threadIdx.x & 63;
  const int cl = lane & 15, quad = lane >> 4;
  const int mtb = (blockIdx.x*4 + wv)*4;
  v8bf a[4][4];
  #pragma unroll
  for (int i = 0; i < 4; ++i)
    #pragma unroll
    for (int kt = 0; kt < 4; ++kt)
      a[i][kt] = *(const v8bf*)&A[((size_t)(mtb+i)*16 + cl)*KP + kt*32 + quad*8];
  for (int nt = 0; nt < NPAD/16; ++nt) {
    const int n = nt*16 + cl;
    v8bf bfr[4];
    #pragma unroll
    for (int kt = 0; kt < 4; ++kt)
      bfr[kt] = *(const v8bf*)&Bp[(size_t)n*KP + kt*32 + quad*8];
    #pragma unroll
    for (int i = 0; i < 4; ++i) {
      v4f acc = {0.f, 0.f, 0.f, 0.f};
      #pragma unroll
      for (int kt = 0; kt < 4; ++kt)
        acc = __builtin_amdgcn_mfma_f32_16x16x32_bf16(a[i][kt], bfr[kt], acc, 0, 0, 0);
      if (n < VSZ) {
        #pragma unroll
        for (int r = 0; r < 4; ++r)
          out[(size_t)((mtb+i)*16 + quad*4 + r)*VSZ + n] = acc[r];
      }
    }
  }
}

// ---------------- launch ----------------
extern "C" void kernel_launch(void* const* d_in, const int* in_sizes, int n_in,
                              void* d_out, int out_size, void* d_ws, size_t ws_size,
                              hipStream_t stream)
{
  (void)in_sizes; (void)n_in; (void)out_size; (void)ws_size;
  const int*   x     = (const int*)d_in[0];
  const float* embed = (const float*)d_in[1];
  const float* Wih0  = (const float*)d_in[2];
  const float* Whh0  = (const float*)d_in[3];
  const float* bih0  = (const float*)d_in[4];
  const float* bhh0  = (const float*)d_in[5];
  const float* Wih1  = (const float*)d_in[6];
  const float* Whh1  = (const float*)d_in[7];
  const float* bih1  = (const float*)d_in[8];
  const float* bhh1  = (const float*)d_in[9];
  const float* gamma = (const float*)d_in[10];
  const float* beta  = (const float*)d_in[11];

  char* ws = (char*)d_ws;
  float* EW   = (float*)(ws + EW_OFF);
  float* b1s  = (float*)(ws + B1S_OFF);
  u16*   W1p  = (u16*)(ws + W1P_OFF);
  u16*   embP = (u16*)(ws + EMBP_OFF);
  u16*   hb0  = (u16*)(ws + HB0_OFF);
  u16*   xg   = (u16*)(ws + XG_OFF);
  float* h1   = (float*)(ws + H1_OFF);
  u16*   h1n  = (u16*)(ws + H1N_OFF);

  k_ew   <<<VSZ, 512, 0, stream>>>(embed, Wih0, bih0, bhh0, EW);
  k_prep2<<<466, 256, 0, stream>>>(Wih1, embed, bih1, bhh1, W1p, embP, b1s);
  k_rec<0><<<BSZ/TB, 512, 0, stream>>>(Whh0, EW, x, nullptr, hb0, nullptr);
  k_xg1  <<<MTOT/256, 256, 0, stream>>>(hb0, W1p, b1s, xg);
  k_rec<1><<<BSZ/TB, 512, 0, stream>>>(Whh1, nullptr, nullptr, xg, nullptr, h1);
  k_ln   <<<MTOT/256, 256, 0, stream>>>(h1, gamma, beta, h1n);
  k_head <<<MTOT/256, 256, 0, stream>>>(h1n, embP, (float*)d_out);
}

// Round 3
// 336.936 us; speedup vs baseline: 2.8717x; 2.8717x over previous
//
#include <hip/hip_runtime.h>

// LSTMNextToken: embed-gather -> 2x LSTM -> LayerNorm -> tied-embedding head.
// I/O dtypes per reference: all float tensors are float32; x is int32.
// Internals use bf16/f16 MFMA where the 2% absmax threshold permits.
//
// Pipeline:
//  k_ew    : EW[v][g] = sum_d embed[v,d]*Wih0[g,d] + bih0[g]+bhh0[g]   (433x480 f32)
//  k_prep2 : bf16 zero-padded copies W1p[480][128], embP[448][128]; b1s=bih1+bhh1 (f32)
//  k_rec<0>: MFMA LSTM layer 0 (gate src = EW gather via x) -> hb0 bf16 [M][128]
//  k_xg1   : MFMA GEMM xg = hb0 @ W1p^T + b1s -> bf16 [M][480]
//  k_rec<1>: MFMA LSTM layer 1 (gate src = xg) -> h1 f32 [M][120]
//  k_ln    : LayerNorm rows -> h1n bf16 [M][128] (pad zeroed; aliases hb0)
//  k_head  : MFMA GEMM logits = h1n @ embP^T -> d_out f32 [M][433]
//
// R3: k_rec rewritten around mfma_f32_16x16x32_f16. Whh lives in registers as
// f16 B-fragments (8 waves x 4 n-tiles, loaded once); h round-trips through
// LDS as packed f16 (A-frag = one ds_read_b128); gates via padded f32 LDS
// (stride 484 -> 2-way banks = free). f16 recurrence keeps error ~8x below
// bf16. R2's k_rec was 83% of runtime with 40% of cycles in LDS bank conflicts.

#define VSZ 433
#define DIM 120
#define BSZ 4096
#define SEQ 16
#define H4  480
#define MTOT (BSZ*SEQ)   // 65536
#define KP  128          // padded K for MFMA
#define NPAD 448         // padded vocab for head
#define TB  16           // batch rows per rec block
#define GP  484          // gates LDS row pad (484%32=4 -> 2-way = free)
#define HP  136          // hLh row pad in f16 (272 B, 16B-aligned rows)

typedef unsigned int   u32;
typedef unsigned short u16;
typedef __attribute__((ext_vector_type(8))) short    v8bf; // 8 x bf16
typedef __attribute__((ext_vector_type(8))) _Float16 v8h;  // 8 x f16
typedef __attribute__((ext_vector_type(4))) float    v4f;  // MFMA acc

__device__ __forceinline__ float bf2f(u16 u){ union{u32 i;float f;}z; z.i=((u32)u)<<16; return z.f; }
__device__ __forceinline__ u16 f2bf(float f){ // RNE
  union{float f;u32 u;}z; z.f=f;
  u32 u = z.u + 0x7fffu + ((z.u>>16)&1u);
  return (u16)(u>>16);
}

// ---------------- workspace layout (bytes, 256-aligned) ----------------
#define EW_OFF   0u          // 433*480*4   = 831360
#define B1S_OFF  831488u     // 480*4       = 1920
#define W1P_OFF  833408u     // 480*128*2   = 122880
#define EMBP_OFF 956288u     // 448*128*2   = 114688
#define HB0_OFF  1070976u    // 65536*128*2 = 16777216
#define XG_OFF   17848192u   // 65536*480*2 = 62914560
#define H1_OFF   80762752u   // 65536*120*4 = 31457280 (end 112220032 ~107 MB)
#define H1N_OFF  HB0_OFF     // alias: hb0 dead after k_xg1

// ---------------- k_ew: EW = embed @ Wih0^T + bih0 + bhh0 ----------------
__global__ __launch_bounds__(512) void k_ew(const float* __restrict__ embed,
                                            const float* __restrict__ Wih0,
                                            const float* __restrict__ bih0,
                                            const float* __restrict__ bhh0,
                                            float* __restrict__ EW)
{
  __shared__ float e[DIM];
  const int v = blockIdx.x, tid = threadIdx.x;
  if (tid < DIM) e[tid] = embed[v*DIM + tid];
  __syncthreads();
  if (tid < H4) {
    float acc = bih0[tid] + bhh0[tid];
    #pragma unroll
    for (int k0 = 0; k0 < DIM; k0 += 4) {
      float4 w = *(const float4*)(Wih0 + tid*DIM + k0);
      acc = fmaf(e[k0+0], w.x, acc);
      acc = fmaf(e[k0+1], w.y, acc);
      acc = fmaf(e[k0+2], w.z, acc);
      acc = fmaf(e[k0+3], w.w, acc);
    }
    EW[v*H4 + tid] = acc;
  }
}

// ---------------- k_prep2: bf16 padded copies + bias sum ----------------
__global__ __launch_bounds__(256) void k_prep2(const float* __restrict__ Wih1,
                                               const float* __restrict__ embed,
                                               const float* __restrict__ bih1,
                                               const float* __restrict__ bhh1,
                                               u16* __restrict__ W1p,
                                               u16* __restrict__ embP,
                                               float* __restrict__ b1s)
{
  const int idx = blockIdx.x*256 + threadIdx.x;
  if (idx < H4*KP) {
    int g = idx >> 7, k = idx & 127;
    W1p[idx] = (k < DIM) ? f2bf(Wih1[g*DIM + k]) : (u16)0;
  } else if (idx < H4*KP + NPAD*KP) {
    int i2 = idx - H4*KP;
    int n = i2 >> 7, k = i2 & 127;
    embP[i2] = (n < VSZ && k < DIM) ? f2bf(embed[n*DIM + k]) : (u16)0;
  } else if (idx < H4*KP + NPAD*KP + H4) {
    int g = idx - (H4*KP + NPAD*KP);
    b1s[g] = bih1[g] + bhh1[g];
  }
}

// ---------------- k_rec: MFMA LSTM layer ----------------
// Block = 512 threads = 8 waves, TB=16 batch rows, 16 timesteps internal.
// Whh f16 B-fragments resident in registers: wave w owns n-tiles w*4..w*4+3
// (tiles >=30 are dead). Per step: A-frags from hLh (packed f16, b128 reads),
// acc init from prefetched src gates, 16 MFMAs, gates -> LDS f32, phase B
// (sigmoid/tanh cell, c-state in regs) -> h back to hLh f16 + global.
template<int LAYER>
__global__ __launch_bounds__(512) void k_rec(const float* __restrict__ Whh,
                                             const float* __restrict__ EW,
                                             const int* __restrict__ x,
                                             const u16* __restrict__ xg,
                                             u16* __restrict__ hb0,
                                             float* __restrict__ h1)
{
  __shared__ float gLs[TB][GP];                    // 30976 B
  __shared__ __align__(16) _Float16 hLh[TB][HP];   //  4352 B
  __shared__ int xL[TB*SEQ];                       //  1024 B (total 36352 B)

  const int tid  = threadIdx.x;
  const int wave = tid >> 6, lane = tid & 63;
  const int cl   = lane & 15, quad = lane >> 4;
  const int b0   = blockIdx.x * TB;

  if (LAYER == 0)
    for (int i = tid; i < TB*SEQ; i += 512) xL[i] = x[b0*SEQ + i];
  for (int i = tid; i < TB*HP; i += 512) (&hLh[0][0])[i] = (_Float16)0.f;
  __syncthreads();

  // ---- resident Whh B-fragments: Bf[i][kt] = Whh[n=nt*16+cl][kt*32+quad*8 ..+7] as f16
  v8h Bf[4][4];
  #pragma unroll
  for (int i = 0; i < 4; ++i) {
    const int nt = wave*4 + i;
    const bool vld = (nt < 30);
    const int n = vld ? nt*16 + cl : 0;
    #pragma unroll
    for (int kt = 0; kt < 4; ++kt) {
      const int k0 = kt*32 + quad*8;
      v8h f = {0,0,0,0,0,0,0,0};
      if (vld && k0 < DIM) {
        float4 q0 = *(const float4*)(Whh + n*DIM + k0);
        float4 q1 = *(const float4*)(Whh + n*DIM + k0 + 4);
        f[0]=(_Float16)q0.x; f[1]=(_Float16)q0.y; f[2]=(_Float16)q0.z; f[3]=(_Float16)q0.w;
        f[4]=(_Float16)q1.x; f[5]=(_Float16)q1.y; f[6]=(_Float16)q1.z; f[7]=(_Float16)q1.w;
      }
      Bf[i][kt] = f;
    }
  }

  // ---- src gate prefetch (one timestep ahead) ----
  float srcv[4][4];
  #pragma unroll
  for (int i = 0; i < 4; ++i)
    #pragma unroll
    for (int r = 0; r < 4; ++r) srcv[i][r] = 0.f;

  auto load_src = [&](int t) {
    #pragma unroll
    for (int i = 0; i < 4; ++i) {
      const int nt = wave*4 + i;
      if (nt < 30) {
        const int n = nt*16 + cl;
        #pragma unroll
        for (int r = 0; r < 4; ++r) {
          const int row = quad*4 + r;
          if (LAYER == 0)
            srcv[i][r] = EW[(size_t)xL[row*SEQ + t]*H4 + n];
          else
            srcv[i][r] = bf2f(xg[((size_t)(b0 + row)*SEQ + t)*H4 + n]);
        }
      }
    }
  };
  load_src(0);

  // phase-B mapping: thread (d, rg) owns rows rg*4..rg*4+3 at dim d
  const int d  = tid % 120;
  const int rg = tid / 120;          // 0..3 active (tid<480)
  float C[4] = {0.f, 0.f, 0.f, 0.f}; // c-state

  for (int t = 0; t < SEQ; ++t) {
    __syncthreads();   // hLh (prev phase B / init) visible
    // A-fragments: one b128 per k-tile
    v8h Af[4];
    #pragma unroll
    for (int kt = 0; kt < 4; ++kt)
      Af[kt] = *(const v8h*)&hLh[cl][kt*32 + quad*8];
    // acc init from src gates
    v4f acc[4];
    #pragma unroll
    for (int i = 0; i < 4; ++i) {
      acc[i][0]=srcv[i][0]; acc[i][1]=srcv[i][1];
      acc[i][2]=srcv[i][2]; acc[i][3]=srcv[i][3];
    }
    // MFMA: gates += h @ Whh^T
    #pragma unroll
    for (int i = 0; i < 4; ++i) {
      if (wave*4 + i < 30) {
        #pragma unroll
        for (int kt = 0; kt < 4; ++kt)
          acc[i] = __builtin_amdgcn_mfma_f32_16x16x32_f16(Af[kt], Bf[i][kt], acc[i], 0, 0, 0);
      }
    }
    if (t + 1 < SEQ) load_src(t + 1);  // overlap next src with MFMA/stores
    // gates -> LDS (D layout: row=quad*4+r, col=cl)
    #pragma unroll
    for (int i = 0; i < 4; ++i) {
      const int nt = wave*4 + i;
      if (nt < 30) {
        #pragma unroll
        for (int r = 0; r < 4; ++r)
          gLs[quad*4 + r][nt*16 + cl] = acc[i][r];
      }
    }
    __syncthreads();   // gates visible
    // phase B: i,f,g,o at offsets 0,120,240,360 (PyTorch order)
    if (tid < 480) {
      #pragma unroll
      for (int r = 0; r < 4; ++r) {
        const int row = rg*4 + r;
        const float gi = gLs[row][d      ];
        const float gf = gLs[row][d + 120];
        const float gg = gLs[row][d + 240];
        const float go = gLs[row][d + 360];
        const float si = 1.f / (1.f + __expf(-gi));
        const float sf = 1.f / (1.f + __expf(-gf));
        const float tg = 1.f - 2.f / (__expf(2.f*gg) + 1.f);
        const float so = 1.f / (1.f + __expf(-go));
        const float c  = sf * C[r] + si * tg;
        C[r] = c;
        const float tc = 1.f - 2.f / (__expf(2.f*c) + 1.f);
        const float h  = so * tc;
        hLh[row][d] = (_Float16)h;
        const size_t m = (size_t)(b0 + row)*SEQ + t;
        if (LAYER == 0) hb0[m*KP + d] = f2bf(h);
        else            h1[m*DIM + d] = h;
      }
    }
  }
}

// ---------------- k_xg1: MFMA GEMM xg = hb0 @ W1p^T + b1s ----------------
__global__ __launch_bounds__(256) void k_xg1(const u16* __restrict__ A,   // [M][128]
                                             const u16* __restrict__ Wp,  // [480][128]
                                             const float* __restrict__ bsum,
                                             u16* __restrict__ xg)        // [M][480]
{
  const int wv = threadIdx.x >> 6, lane = threadIdx.x & 63;
  const int cl = lane & 15, quad = lane >> 4;
  const int mtb = (blockIdx.x*4 + wv)*4;   // first of 4 m-tiles
  v8bf a[4][4];
  #pragma unroll
  for (int i = 0; i < 4; ++i)
    #pragma unroll
    for (int kt = 0; kt < 4; ++kt)
      a[i][kt] = *(const v8bf*)&A[((size_t)(mtb+i)*16 + cl)*KP + kt*32 + quad*8];
  for (int nt = 0; nt < H4/16; ++nt) {
    const int n = nt*16 + cl;
    v8bf bfr[4];
    #pragma unroll
    for (int kt = 0; kt < 4; ++kt)
      bfr[kt] = *(const v8bf*)&Wp[(size_t)n*KP + kt*32 + quad*8];
    const float bias = bsum[n];
    #pragma unroll
    for (int i = 0; i < 4; ++i) {
      v4f acc = {bias, bias, bias, bias};
      #pragma unroll
      for (int kt = 0; kt < 4; ++kt)
        acc = __builtin_amdgcn_mfma_f32_16x16x32_bf16(a[i][kt], bfr[kt], acc, 0, 0, 0);
      #pragma unroll
      for (int r = 0; r < 4; ++r)
        xg[(size_t)((mtb+i)*16 + quad*4 + r)*H4 + n] = f2bf(acc[r]);
    }
  }
}

// ---------------- k_ln: LayerNorm rows of h1 -> h1n (bf16, padded) ----------------
__global__ __launch_bounds__(256) void k_ln(const float* __restrict__ h1,
                                            const float* __restrict__ gamma,
                                            const float* __restrict__ beta,
                                            u16* __restrict__ h1n)
{
  const int m = blockIdx.x*256 + threadIdx.x;
  const float* row = h1 + (size_t)m*DIM;
  float v[DIM];
  float s = 0.f;
  #pragma unroll
  for (int i = 0; i < DIM/4; ++i) {
    float4 q = *(const float4*)(row + i*4);
    v[i*4+0]=q.x; v[i*4+1]=q.y; v[i*4+2]=q.z; v[i*4+3]=q.w;
    s += q.x + q.y + q.z + q.w;
  }
  const float mu = s * (1.f/DIM);
  float s2 = 0.f;
  #pragma unroll
  for (int i = 0; i < DIM; ++i) { float dd = v[i]-mu; s2 = fmaf(dd, dd, s2); }
  const float rstd = rsqrtf(s2*(1.f/DIM) + 1e-5f);
  u32* dst = (u32*)(h1n + (size_t)m*KP);
  #pragma unroll
  for (int i = 0; i < DIM/2; ++i) {
    u16 lo = f2bf(fmaf((v[2*i  ]-mu)*rstd, gamma[2*i  ], beta[2*i  ]));
    u16 hi = f2bf(fmaf((v[2*i+1]-mu)*rstd, gamma[2*i+1], beta[2*i+1]));
    dst[i] = (u32)lo | ((u32)hi << 16);
  }
  dst[60] = 0u; dst[61] = 0u; dst[62] = 0u; dst[63] = 0u;  // zero pad cols 120..127
}

// ---------------- k_head: MFMA GEMM logits = h1n @ embP^T (f32 out) ----------------
__global__ __launch_bounds__(256) void k_head(const u16* __restrict__ A,   // [M][128]
                                              const u16* __restrict__ Bp,  // [448][128]
                                              float* __restrict__ out)     // [M][433]
{
  const int wv = threadIdx.x >> 6, lane = threadIdx.x & 63;
  const int cl = lane & 15, quad = lane >> 4;
  const int mtb = (blockIdx.x*4 + wv)*4;
  v8bf a[4][4];
  #pragma unroll
  for (int i = 0; i < 4; ++i)
    #pragma unroll
    for (int kt = 0; kt < 4; ++kt)
      a[i][kt] = *(const v8bf*)&A[((size_t)(mtb+i)*16 + cl)*KP + kt*32 + quad*8];
  for (int nt = 0; nt < NPAD/16; ++nt) {
    const int n = nt*16 + cl;
    v8bf bfr[4];
    #pragma unroll
    for (int kt = 0; kt < 4; ++kt)
      bfr[kt] = *(const v8bf*)&Bp[(size_t)n*KP + kt*32 + quad*8];
    #pragma unroll
    for (int i = 0; i < 4; ++i) {
      v4f acc = {0.f, 0.f, 0.f, 0.f};
      #pragma unroll
      for (int kt = 0; kt < 4; ++kt)
        acc = __builtin_amdgcn_mfma_f32_16x16x32_bf16(a[i][kt], bfr[kt], acc, 0, 0, 0);
      if (n < VSZ) {
        #pragma unroll
        for (int r = 0; r < 4; ++r)
          out[(size_t)((mtb+i)*16 + quad*4 + r)*VSZ + n] = acc[r];
      }
    }
  }
}

// ---------------- launch ----------------
extern "C" void kernel_launch(void* const* d_in, const int* in_sizes, int n_in,
                              void* d_out, int out_size, void* d_ws, size_t ws_size,
                              hipStream_t stream)
{
  (void)in_sizes; (void)n_in; (void)out_size; (void)ws_size;
  const int*   x     = (const int*)d_in[0];
  const float* embed = (const float*)d_in[1];
  const float* Wih0  = (const float*)d_in[2];
  const float* Whh0  = (const float*)d_in[3];
  const float* bih0  = (const float*)d_in[4];
  const float* bhh0  = (const float*)d_in[5];
  const float* Wih1  = (const float*)d_in[6];
  const float* Whh1  = (const float*)d_in[7];
  const float* bih1  = (const float*)d_in[8];
  const float* bhh1  = (const float*)d_in[9];
  const float* gamma = (const float*)d_in[10];
  const float* beta  = (const float*)d_in[11];

  char* ws = (char*)d_ws;
  float* EW   = (float*)(ws + EW_OFF);
  float* b1s  = (float*)(ws + B1S_OFF);
  u16*   W1p  = (u16*)(ws + W1P_OFF);
  u16*   embP = (u16*)(ws + EMBP_OFF);
  u16*   hb0  = (u16*)(ws + HB0_OFF);
  u16*   xg   = (u16*)(ws + XG_OFF);
  float* h1   = (float*)(ws + H1_OFF);
  u16*   h1n  = (u16*)(ws + H1N_OFF);

  k_ew   <<<VSZ, 512, 0, stream>>>(embed, Wih0, bih0, bhh0, EW);
  k_prep2<<<466, 256, 0, stream>>>(Wih1, embed, bih1, bhh1, W1p, embP, b1s);
  k_rec<0><<<BSZ/TB, 512, 0, stream>>>(Whh0, EW, x, nullptr, hb0, nullptr);
  k_xg1  <<<MTOT/256, 256, 0, stream>>>(hb0, W1p, b1s, xg);
  k_rec<1><<<BSZ/TB, 512, 0, stream>>>(Whh1, nullptr, nullptr, xg, nullptr, h1);
  k_ln   <<<MTOT/256, 256, 0, stream>>>(h1, gamma, beta, h1n);
  k_head <<<MTOT/256, 256, 0, stream>>>(h1n, embP, (float*)d_out);
}

// Round 4
// 295.985 us; speedup vs baseline: 3.2691x; 1.1384x over previous
//
#include <hip/hip_runtime.h>

// LSTMNextToken: embed-gather -> 2x LSTM -> LayerNorm -> tied-embedding head.
// I/O dtypes: float tensors are float32; x is int32. Internals f16/bf16 MFMA.
//
// R4 pipeline (fused):
//  k_ew    : EW[v][g] = embed[v]@Wih0^T + bih0 + bhh0       (433x480 f32, L2-resident)
//  k_prep2 : embP bf16 [448][128] zero-padded; b1s = bih1+bhh1 (f32)
//  k_rec0  : MFMA LSTM layer 0 (src = EW gather) -> hb0 f16 [SEQ][B][128] t-major
//  k_rec1  : MFMA LSTM layer 1, FUSED: src-GEMM (hb0@Wih1^T via resident f16
//            frags) + rec-GEMM (h1@Whh1^T) + bias + LayerNorm -> h1n bf16 [M][128]
//  k_head  : MFMA GEMM logits = h1n @ embP^T -> d_out f32 [M][433]
// R3->R4: deleted k_xg1/k_ln and xg(126MB)/h1(62MB) round-trips; 7->5 launches.

#define VSZ 433
#define DIM 120
#define BSZ 4096
#define SEQ 16
#define H4  480
#define MTOT (BSZ*SEQ)   // 65536
#define KP  128          // padded K for MFMA
#define NPAD 448         // padded vocab for head
#define TB  16           // batch rows per rec block
#define GP  484          // gates LDS row pad (484%32=4 -> 2-way banks = free)
#define HP  136          // h-state LDS row pad in f16 (2-way banks on b128)

typedef unsigned int   u32;
typedef unsigned short u16;
typedef __attribute__((ext_vector_type(8))) short    v8bf; // 8 x bf16
typedef __attribute__((ext_vector_type(8))) _Float16 v8h;  // 8 x f16
typedef __attribute__((ext_vector_type(4))) float    v4f;  // MFMA acc

__device__ __forceinline__ float bf2f(u16 u){ union{u32 i;float f;}z; z.i=((u32)u)<<16; return z.f; }
__device__ __forceinline__ u16 f2bf(float f){ // RNE
  union{float f;u32 u;}z; z.f=f;
  u32 u = z.u + 0x7fffu + ((z.u>>16)&1u);
  return (u16)(u>>16);
}

// ---------------- workspace layout (bytes, 256-aligned) ----------------
#define EW_OFF   0u          // 433*480*4   = 831360
#define B1S_OFF  831488u     // 480*4       = 1920
#define EMBP_OFF 833408u     // 448*128*2   = 114688
#define HB0_OFF  948096u     // 65536*128*2 = 16777216  (f16, t-major)
#define H1N_OFF  17725312u   // 65536*128*2 = 16777216  (end ~34.5 MB)

// ---------------- k_ew ----------------
__global__ __launch_bounds__(512) void k_ew(const float* __restrict__ embed,
                                            const float* __restrict__ Wih0,
                                            const float* __restrict__ bih0,
                                            const float* __restrict__ bhh0,
                                            float* __restrict__ EW)
{
  __shared__ float e[DIM];
  const int v = blockIdx.x, tid = threadIdx.x;
  if (tid < DIM) e[tid] = embed[v*DIM + tid];
  __syncthreads();
  if (tid < H4) {
    float acc = bih0[tid] + bhh0[tid];
    #pragma unroll
    for (int k0 = 0; k0 < DIM; k0 += 4) {
      float4 w = *(const float4*)(Wih0 + tid*DIM + k0);
      acc = fmaf(e[k0+0], w.x, acc);
      acc = fmaf(e[k0+1], w.y, acc);
      acc = fmaf(e[k0+2], w.z, acc);
      acc = fmaf(e[k0+3], w.w, acc);
    }
    EW[v*H4 + tid] = acc;
  }
}

// ---------------- k_prep2: embP bf16 padded + b1s ----------------
__global__ __launch_bounds__(256) void k_prep2(const float* __restrict__ embed,
                                               const float* __restrict__ bih1,
                                               const float* __restrict__ bhh1,
                                               u16* __restrict__ embP,
                                               float* __restrict__ b1s)
{
  const int idx = blockIdx.x*256 + threadIdx.x;
  if (idx < NPAD*KP) {
    int n = idx >> 7, k = idx & 127;
    embP[idx] = (n < VSZ && k < DIM) ? f2bf(embed[n*DIM + k]) : (u16)0;
  } else if (idx < NPAD*KP + H4) {
    int g = idx - NPAD*KP;
    b1s[g] = bih1[g] + bhh1[g];
  }
}

// ---------------- k_rec0: MFMA LSTM layer 0 ----------------
// 512 thr = 8 waves; wave owns n-tiles wave*4..+3 (>=30 dead). Whh0 resident
// f16 B-frags. src gates = EW gather (prefetched 1 step). Output h -> LDS f16
// (next-step A-frags) + hb0 global f16, t-major, pads zeroed by threads 480+.
__global__ __launch_bounds__(512) void k_rec0(const float* __restrict__ Whh,
                                              const float* __restrict__ EW,
                                              const int* __restrict__ x,
                                              _Float16* __restrict__ hb0)
{
  __shared__ float gLs[TB][GP];                    // 30976 B
  __shared__ __align__(16) _Float16 hLh[TB][HP];   //  4352 B
  __shared__ int xL[TB*SEQ];                       //  1024 B

  const int tid  = threadIdx.x;
  const int wave = tid >> 6, lane = tid & 63;
  const int cl   = lane & 15, quad = lane >> 4;
  const int b0   = blockIdx.x * TB;

  for (int i = tid; i < TB*SEQ; i += 512) xL[i] = x[b0*SEQ + i];
  for (int i = tid; i < TB*HP; i += 512) (&hLh[0][0])[i] = (_Float16)0.f;
  __syncthreads();

  v8h Bf[4][4];
  #pragma unroll
  for (int i = 0; i < 4; ++i) {
    const int nt = wave*4 + i;
    const bool vld = (nt < 30);
    const int n = vld ? nt*16 + cl : 0;
    #pragma unroll
    for (int kt = 0; kt < 4; ++kt) {
      const int k0 = kt*32 + quad*8;
      v8h f = {0,0,0,0,0,0,0,0};
      if (vld && k0 < DIM) {
        float4 q0 = *(const float4*)(Whh + n*DIM + k0);
        float4 q1 = *(const float4*)(Whh + n*DIM + k0 + 4);
        f[0]=(_Float16)q0.x; f[1]=(_Float16)q0.y; f[2]=(_Float16)q0.z; f[3]=(_Float16)q0.w;
        f[4]=(_Float16)q1.x; f[5]=(_Float16)q1.y; f[6]=(_Float16)q1.z; f[7]=(_Float16)q1.w;
      }
      Bf[i][kt] = f;
    }
  }

  float srcv[4][4];
  auto load_src = [&](int t) {
    #pragma unroll
    for (int i = 0; i < 4; ++i) {
      const int nt = wave*4 + i;
      if (nt < 30) {
        const int n = nt*16 + cl;
        #pragma unroll
        for (int r = 0; r < 4; ++r)
          srcv[i][r] = EW[(size_t)xL[(quad*4 + r)*SEQ + t]*H4 + n];
      }
    }
  };
  load_src(0);

  const int d  = tid % 120;
  const int rg = tid / 120;
  float C[4] = {0.f, 0.f, 0.f, 0.f};

  for (int t = 0; t < SEQ; ++t) {
    __syncthreads();   // hLh visible
    v8h Af[4];
    #pragma unroll
    for (int kt = 0; kt < 4; ++kt)
      Af[kt] = *(const v8h*)&hLh[cl][kt*32 + quad*8];
    v4f acc[4];
    #pragma unroll
    for (int i = 0; i < 4; ++i) {
      acc[i][0]=srcv[i][0]; acc[i][1]=srcv[i][1];
      acc[i][2]=srcv[i][2]; acc[i][3]=srcv[i][3];
    }
    #pragma unroll
    for (int i = 0; i < 4; ++i)
      if (wave*4 + i < 30) {
        #pragma unroll
        for (int kt = 0; kt < 4; ++kt)
          acc[i] = __builtin_amdgcn_mfma_f32_16x16x32_f16(Af[kt], Bf[i][kt], acc[i], 0, 0, 0);
      }
    if (t + 1 < SEQ) load_src(t + 1);
    #pragma unroll
    for (int i = 0; i < 4; ++i) {
      const int nt = wave*4 + i;
      if (nt < 30) {
        #pragma unroll
        for (int r = 0; r < 4; ++r)
          gLs[quad*4 + r][nt*16 + cl] = acc[i][r];
      }
    }
    __syncthreads();   // gates visible
    if (tid < 480) {
      #pragma unroll
      for (int r = 0; r < 4; ++r) {
        const int row = rg*4 + r;
        const float gi = gLs[row][d      ];
        const float gf = gLs[row][d + 120];
        const float gg = gLs[row][d + 240];
        const float go = gLs[row][d + 360];
        const float si = 1.f / (1.f + __expf(-gi));
        const float sf = 1.f / (1.f + __expf(-gf));
        const float tg = 1.f - 2.f / (__expf(2.f*gg) + 1.f);
        const float so = 1.f / (1.f + __expf(-go));
        const float c  = sf * C[r] + si * tg;
        C[r] = c;
        const float tc = 1.f - 2.f / (__expf(2.f*c) + 1.f);
        const float h  = so * tc;
        hLh[row][d] = (_Float16)h;
        hb0[((size_t)t*BSZ + b0 + row)*KP + d] = (_Float16)h;
      }
    } else {
      const int i = tid - 480;       // zero pad cols 120..127 (16 rows x 8)
      #pragma unroll
      for (int j = 0; j < 4; ++j) {
        const int idx = i*4 + j, row = idx >> 3, col = 120 + (idx & 7);
        hb0[((size_t)t*BSZ + b0 + row)*KP + col] = (_Float16)0.f;
      }
    }
  }
}

// ---------------- k_rec1: fused src-GEMM + LSTM + LayerNorm ----------------
// gates = b1s + hb0[t]@Wih1^T + h1@Whh1^T   (both weight sets resident f16 frags)
// phase B -> h; fused LN (2-stage LDS reduction) -> h1n bf16 [M][128].
__global__ __launch_bounds__(512) void k_rec1(const float* __restrict__ Wih1,
                                              const float* __restrict__ Whh1,
                                              const float* __restrict__ b1s,
                                              const _Float16* __restrict__ hb0,
                                              const float* __restrict__ gamma,
                                              const float* __restrict__ beta,
                                              u16* __restrict__ h1n)
{
  __shared__ float gLs[TB][GP];                    // 30976 B
  __shared__ __align__(16) _Float16 hLh[TB][HP];   //  4352 B

  const int tid  = threadIdx.x;
  const int wave = tid >> 6, lane = tid & 63;
  const int cl   = lane & 15, quad = lane >> 4;
  const int b0   = blockIdx.x * TB;

  for (int i = tid; i < TB*HP; i += 512) (&hLh[0][0])[i] = (_Float16)0.f;

  v8h Bi[4][4], Bh[4][4];
  float bias[4];
  #pragma unroll
  for (int i = 0; i < 4; ++i) {
    const int nt = wave*4 + i;
    const bool vld = (nt < 30);
    const int n = vld ? nt*16 + cl : 0;
    bias[i] = vld ? b1s[n] : 0.f;
    #pragma unroll
    for (int kt = 0; kt < 4; ++kt) {
      const int k0 = kt*32 + quad*8;
      v8h fi = {0,0,0,0,0,0,0,0}, fh = {0,0,0,0,0,0,0,0};
      if (vld && k0 < DIM) {
        float4 q0 = *(const float4*)(Wih1 + n*DIM + k0);
        float4 q1 = *(const float4*)(Wih1 + n*DIM + k0 + 4);
        fi[0]=(_Float16)q0.x; fi[1]=(_Float16)q0.y; fi[2]=(_Float16)q0.z; fi[3]=(_Float16)q0.w;
        fi[4]=(_Float16)q1.x; fi[5]=(_Float16)q1.y; fi[6]=(_Float16)q1.z; fi[7]=(_Float16)q1.w;
        float4 p0 = *(const float4*)(Whh1 + n*DIM + k0);
        float4 p1 = *(const float4*)(Whh1 + n*DIM + k0 + 4);
        fh[0]=(_Float16)p0.x; fh[1]=(_Float16)p0.y; fh[2]=(_Float16)p0.z; fh[3]=(_Float16)p0.w;
        fh[4]=(_Float16)p1.x; fh[5]=(_Float16)p1.y; fh[6]=(_Float16)p1.z; fh[7]=(_Float16)p1.w;
      }
      Bi[i][kt] = fi;
      Bh[i][kt] = fh;
    }
  }

  const int d  = tid % 120;
  const int rg = tid / 120;
  const float gmm = (tid < 480) ? gamma[d] : 0.f;
  const float bta = (tid < 480) ? beta[d]  : 0.f;
  float C[4] = {0.f, 0.f, 0.f, 0.f};
  __syncthreads();

  for (int t = 0; t < SEQ; ++t) {
    // A0: layer-0 h for (b0+cl, t) from global (t-major -> contiguous block)
    v8h A0[4], A1[4];
    #pragma unroll
    for (int kt = 0; kt < 4; ++kt)
      A0[kt] = *(const v8h*)&hb0[((size_t)t*BSZ + b0 + cl)*KP + kt*32 + quad*8];
    #pragma unroll
    for (int kt = 0; kt < 4; ++kt)
      A1[kt] = *(const v8h*)&hLh[cl][kt*32 + quad*8];
    v4f acc[4];
    #pragma unroll
    for (int i = 0; i < 4; ++i)
      acc[i] = (v4f){bias[i], bias[i], bias[i], bias[i]};
    #pragma unroll
    for (int i = 0; i < 4; ++i)
      if (wave*4 + i < 30) {
        #pragma unroll
        for (int kt = 0; kt < 4; ++kt) {
          acc[i] = __builtin_amdgcn_mfma_f32_16x16x32_f16(A0[kt], Bi[i][kt], acc[i], 0, 0, 0);
          acc[i] = __builtin_amdgcn_mfma_f32_16x16x32_f16(A1[kt], Bh[i][kt], acc[i], 0, 0, 0);
        }
      }
    #pragma unroll
    for (int i = 0; i < 4; ++i) {
      const int nt = wave*4 + i;
      if (nt < 30) {
        #pragma unroll
        for (int r = 0; r < 4; ++r)
          gLs[quad*4 + r][nt*16 + cl] = acc[i][r];
      }
    }
    __syncthreads();   // gates visible
    float hreg[4];
    if (tid < 480) {
      #pragma unroll
      for (int r = 0; r < 4; ++r) {
        const int row = rg*4 + r;
        const float gi = gLs[row][d      ];
        const float gf = gLs[row][d + 120];
        const float gg = gLs[row][d + 240];
        const float go = gLs[row][d + 360];
        const float si = 1.f / (1.f + __expf(-gi));
        const float sf = 1.f / (1.f + __expf(-gf));
        const float tg = 1.f - 2.f / (__expf(2.f*gg) + 1.f);
        const float so = 1.f / (1.f + __expf(-go));
        const float c  = sf * C[r] + si * tg;
        C[r] = c;
        const float tc = 1.f - 2.f / (__expf(2.f*c) + 1.f);
        const float h  = so * tc;
        hreg[r] = h;
        hLh[row][d] = (_Float16)h;   // next-step A1
        gLs[row][d] = h;             // LN input (gate-i slot, safe: sole reader)
      }
    }
    __syncthreads();   // h values visible for LN
    if (tid < 128) {   // stage 1: 8 segments x 15 elems per row
      const int row = tid >> 3, seg = tid & 7;
      float s1 = 0.f, s2 = 0.f;
      #pragma unroll
      for (int j = 0; j < 15; ++j) {
        const float v = gLs[row][seg*15 + j];
        s1 += v; s2 = fmaf(v, v, s2);
      }
      gLs[row][464 + seg] = s1;
      gLs[row][472 + seg] = s2;
    }
    __syncthreads();
    if (tid < 16) {    // stage 2: mu / rstd per row
      float s1 = 0.f, s2 = 0.f;
      #pragma unroll
      for (int j = 0; j < 8; ++j) { s1 += gLs[tid][464 + j]; s2 += gLs[tid][472 + j]; }
      const float mu = s1 * (1.f/DIM);
      const float var = s2 * (1.f/DIM) - mu*mu;
      gLs[tid][480] = mu;
      gLs[tid][481] = rsqrtf(var + 1e-5f);
    }
    __syncthreads();
    if (tid < 480) {
      #pragma unroll
      for (int r = 0; r < 4; ++r) {
        const int row = rg*4 + r;
        const float mu = gLs[row][480], rs = gLs[row][481];
        const float v = fmaf((hreg[r] - mu)*rs, gmm, bta);
        h1n[((size_t)(b0 + row)*SEQ + t)*KP + d] = f2bf(v);
      }
    } else {
      const int i = tid - 480;       // zero pad cols 120..127
      #pragma unroll
      for (int j = 0; j < 4; ++j) {
        const int idx = i*4 + j, row = idx >> 3, col = 120 + (idx & 7);
        h1n[((size_t)(b0 + row)*SEQ + t)*KP + col] = (u16)0;
      }
    }
    __syncthreads();   // protect gLs/hLh before next step overwrites
  }
}

// ---------------- k_head: MFMA GEMM logits = h1n @ embP^T (f32 out) ----------------
__global__ __launch_bounds__(256) void k_head(const u16* __restrict__ A,   // [M][128]
                                              const u16* __restrict__ Bp,  // [448][128]
                                              float* __restrict__ out)     // [M][433]
{
  const int wv = threadIdx.x >> 6, lane = threadIdx.x & 63;
  const int cl = lane & 15, quad = lane >> 4;
  const int mtb = (blockIdx.x*4 + wv)*4;
  v8bf a[4][4];
  #pragma unroll
  for (int i = 0; i < 4; ++i)
    #pragma unroll
    for (int kt = 0; kt < 4; ++kt)
      a[i][kt] = *(const v8bf*)&A[((size_t)(mtb+i)*16 + cl)*KP + kt*32 + quad*8];
  for (int nt = 0; nt < NPAD/16; ++nt) {
    const int n = nt*16 + cl;
    v8bf bfr[4];
    #pragma unroll
    for (int kt = 0; kt < 4; ++kt)
      bfr[kt] = *(const v8bf*)&Bp[(size_t)n*KP + kt*32 + quad*8];
    #pragma unroll
    for (int i = 0; i < 4; ++i) {
      v4f acc = {0.f, 0.f, 0.f, 0.f};
      #pragma unroll
      for (int kt = 0; kt < 4; ++kt)
        acc = __builtin_amdgcn_mfma_f32_16x16x32_bf16(a[i][kt], bfr[kt], acc, 0, 0, 0);
      if (n < VSZ) {
        #pragma unroll
        for (int r = 0; r < 4; ++r)
          out[(size_t)((mtb+i)*16 + quad*4 + r)*VSZ + n] = acc[r];
      }
    }
  }
}

// ---------------- launch ----------------
extern "C" void kernel_launch(void* const* d_in, const int* in_sizes, int n_in,
                              void* d_out, int out_size, void* d_ws, size_t ws_size,
                              hipStream_t stream)
{
  (void)in_sizes; (void)n_in; (void)out_size; (void)ws_size;
  const int*   x     = (const int*)d_in[0];
  const float* embed = (const float*)d_in[1];
  const float* Wih0  = (const float*)d_in[2];
  const float* Whh0  = (const float*)d_in[3];
  const float* bih0  = (const float*)d_in[4];
  const float* bhh0  = (const float*)d_in[5];
  const float* Wih1  = (const float*)d_in[6];
  const float* Whh1  = (const float*)d_in[7];
  const float* bih1  = (const float*)d_in[8];
  const float* bhh1  = (const float*)d_in[9];
  const float* gamma = (const float*)d_in[10];
  const float* beta  = (const float*)d_in[11];

  char* ws = (char*)d_ws;
  float*     EW   = (float*)(ws + EW_OFF);
  float*     b1s  = (float*)(ws + B1S_OFF);
  u16*       embP = (u16*)(ws + EMBP_OFF);
  _Float16*  hb0  = (_Float16*)(ws + HB0_OFF);
  u16*       h1n  = (u16*)(ws + H1N_OFF);

  k_ew   <<<VSZ, 512, 0, stream>>>(embed, Wih0, bih0, bhh0, EW);
  k_prep2<<<226, 256, 0, stream>>>(embed, bih1, bhh1, embP, b1s);
  k_rec0 <<<BSZ/TB, 512, 0, stream>>>(Whh0, EW, x, hb0);
  k_rec1 <<<BSZ/TB, 512, 0, stream>>>(Wih1, Whh1, b1s, hb0, gamma, beta, h1n);
  k_head <<<MTOT/256, 256, 0, stream>>>(h1n, embP, (float*)d_out);
}

// Round 5
// 288.084 us; speedup vs baseline: 3.3587x; 1.0274x over previous
//
#include <hip/hip_runtime.h>

// LSTMNextToken: embed-gather -> 2x LSTM -> LayerNorm -> tied-embedding head.
// I/O dtypes: float tensors are float32; x is int32. Internals f16/bf16 MFMA.
//
// R5 pipeline:
//  k_ew    : EW[v][g] = embed[v]@Wih0^T + bih0 + bhh0       (433x480 f32, L2-resident)
//  k_prep2 : embP bf16 [448][128] zero-padded; b1s = bih1+bhh1 (f32)
//  k_rec0  : MFMA LSTM layer 0 (src = EW gather, prefetched) -> hb0 f16 t-major
//  k_rec1  : MFMA LSTM layer 1 + fused src-GEMM + shuffle-LayerNorm -> h1n bf16
//  k_head  : MFMA GEMM logits = h1n @ embP^T -> d_out f32 [M][433]
// R4->R5: k_rec1 5->2 barriers/step (shuffle-LN), A0 global loads prefetched
// one step ahead (registers), phase B remapped wave-owns-2-rows with b64/b32
// vectorized LDS+global access. k_rec1 was 73 us latency-bound (VALUBusy 33%,
// MfmaUtil 8%) with global-load latency + 5 barriers on the serial t-chain.

#define VSZ 433
#define DIM 120
#define BSZ 4096
#define SEQ 16
#define H4  480
#define MTOT (BSZ*SEQ)   // 65536
#define KP  128          // padded K for MFMA
#define NPAD 448         // padded vocab for head
#define TB  16           // batch rows per rec block
#define GP  484          // gates LDS row pad (484%32=4 -> 2-way banks = free)
#define HP  136          // h-state LDS row pad in f16 (2-way banks on b128)

typedef unsigned int   u32;
typedef unsigned short u16;
typedef __attribute__((ext_vector_type(8))) short    v8bf; // 8 x bf16
typedef __attribute__((ext_vector_type(8))) _Float16 v8h;  // 8 x f16
typedef __attribute__((ext_vector_type(4))) float    v4f;  // MFMA acc

__device__ __forceinline__ float bf2f(u16 u){ union{u32 i;float f;}z; z.i=((u32)u)<<16; return z.f; }
__device__ __forceinline__ u16 f2bf(float f){ // RNE
  union{float f;u32 u;}z; z.f=f;
  u32 u = z.u + 0x7fffu + ((z.u>>16)&1u);
  return (u16)(u>>16);
}
__device__ __forceinline__ u32 packh2(float a, float b){
  union{_Float16 h[2]; u32 u;} z;
  z.h[0] = (_Float16)a; z.h[1] = (_Float16)b;
  return z.u;
}

// ---------------- workspace layout (bytes, 256-aligned) ----------------
#define EW_OFF   0u          // 433*480*4   = 831360
#define B1S_OFF  831488u     // 480*4       = 1920
#define EMBP_OFF 833408u     // 448*128*2   = 114688
#define HB0_OFF  948096u     // 65536*128*2 = 16777216  (f16, t-major)
#define H1N_OFF  17725312u   // 65536*128*2 = 16777216  (end ~34.5 MB)

// ---------------- k_ew ----------------
__global__ __launch_bounds__(512) void k_ew(const float* __restrict__ embed,
                                            const float* __restrict__ Wih0,
                                            const float* __restrict__ bih0,
                                            const float* __restrict__ bhh0,
                                            float* __restrict__ EW)
{
  __shared__ float e[DIM];
  const int v = blockIdx.x, tid = threadIdx.x;
  if (tid < DIM) e[tid] = embed[v*DIM + tid];
  __syncthreads();
  if (tid < H4) {
    float acc = bih0[tid] + bhh0[tid];
    #pragma unroll
    for (int k0 = 0; k0 < DIM; k0 += 4) {
      float4 w = *(const float4*)(Wih0 + tid*DIM + k0);
      acc = fmaf(e[k0+0], w.x, acc);
      acc = fmaf(e[k0+1], w.y, acc);
      acc = fmaf(e[k0+2], w.z, acc);
      acc = fmaf(e[k0+3], w.w, acc);
    }
    EW[v*H4 + tid] = acc;
  }
}

// ---------------- k_prep2: embP bf16 padded + b1s ----------------
__global__ __launch_bounds__(256) void k_prep2(const float* __restrict__ embed,
                                               const float* __restrict__ bih1,
                                               const float* __restrict__ bhh1,
                                               u16* __restrict__ embP,
                                               float* __restrict__ b1s)
{
  const int idx = blockIdx.x*256 + threadIdx.x;
  if (idx < NPAD*KP) {
    int n = idx >> 7, k = idx & 127;
    embP[idx] = (n < VSZ && k < DIM) ? f2bf(embed[n*DIM + k]) : (u16)0;
  } else if (idx < NPAD*KP + H4) {
    int g = idx - NPAD*KP;
    b1s[g] = bih1[g] + bhh1[g];
  }
}

// ---------------- k_rec0: MFMA LSTM layer 0 ----------------
// 512 thr = 8 waves. MFMA: wave owns n-tiles wave*4..+3 (>=30 dead), Whh0
// resident f16 B-frags, src = EW gather prefetched 1 step. Phase B: wave owns
// rows {2w,2w+1}, lane l<60 owns dims {2l,2l+1} (b64 gate reads, b32 stores;
// lanes 60-63 write the hb0 pad cols). 2 barriers/step.
__global__ __launch_bounds__(512) void k_rec0(const float* __restrict__ Whh,
                                              const float* __restrict__ EW,
                                              const int* __restrict__ x,
                                              _Float16* __restrict__ hb0)
{
  __shared__ float gLs[TB][GP];                    // 30976 B
  __shared__ __align__(16) _Float16 hLh[TB][HP];   //  4352 B
  __shared__ int xL[TB*SEQ];                       //  1024 B

  const int tid  = threadIdx.x;
  const int wave = tid >> 6, lane = tid & 63;
  const int cl   = lane & 15, quad = lane >> 4;
  const int b0   = blockIdx.x * TB;

  for (int i = tid; i < TB*SEQ; i += 512) xL[i] = x[b0*SEQ + i];
  for (int i = tid; i < TB*HP; i += 512) (&hLh[0][0])[i] = (_Float16)0.f;
  __syncthreads();

  v8h Bf[4][4];
  #pragma unroll
  for (int i = 0; i < 4; ++i) {
    const int nt = wave*4 + i;
    const bool vld = (nt < 30);
    const int n = vld ? nt*16 + cl : 0;
    #pragma unroll
    for (int kt = 0; kt < 4; ++kt) {
      const int k0 = kt*32 + quad*8;
      v8h f = {0,0,0,0,0,0,0,0};
      if (vld && k0 < DIM) {
        float4 q0 = *(const float4*)(Whh + n*DIM + k0);
        float4 q1 = *(const float4*)(Whh + n*DIM + k0 + 4);
        f[0]=(_Float16)q0.x; f[1]=(_Float16)q0.y; f[2]=(_Float16)q0.z; f[3]=(_Float16)q0.w;
        f[4]=(_Float16)q1.x; f[5]=(_Float16)q1.y; f[6]=(_Float16)q1.z; f[7]=(_Float16)q1.w;
      }
      Bf[i][kt] = f;
    }
  }

  float srcv[4][4];
  auto load_src = [&](int t) {
    #pragma unroll
    for (int i = 0; i < 4; ++i) {
      const int nt = wave*4 + i;
      if (nt < 30) {
        const int n = nt*16 + cl;
        #pragma unroll
        for (int r = 0; r < 4; ++r)
          srcv[i][r] = EW[(size_t)xL[(quad*4 + r)*SEQ + t]*H4 + n];
      }
    }
  };
  load_src(0);

  // phase-B mapping: wave owns rows {2w,2w+1}; lane l<60 owns dims {2l,2l+1}
  const int prow = wave*2;
  const bool act = lane < 60;
  const int d0   = lane*2;
  float C[2][2] = {{0.f,0.f},{0.f,0.f}};

  for (int t = 0; t < SEQ; ++t) {
    __syncthreads();   // hLh (prev phase B / init) visible
    v8h Af[4];
    #pragma unroll
    for (int kt = 0; kt < 4; ++kt)
      Af[kt] = *(const v8h*)&hLh[cl][kt*32 + quad*8];
    v4f acc[4];
    #pragma unroll
    for (int i = 0; i < 4; ++i) {
      acc[i][0]=srcv[i][0]; acc[i][1]=srcv[i][1];
      acc[i][2]=srcv[i][2]; acc[i][3]=srcv[i][3];
    }
    #pragma unroll
    for (int i = 0; i < 4; ++i)
      if (wave*4 + i < 30) {
        #pragma unroll
        for (int kt = 0; kt < 4; ++kt)
          acc[i] = __builtin_amdgcn_mfma_f32_16x16x32_f16(Af[kt], Bf[i][kt], acc[i], 0, 0, 0);
      }
    if (t + 1 < SEQ) load_src(t + 1);
    #pragma unroll
    for (int i = 0; i < 4; ++i) {
      const int nt = wave*4 + i;
      if (nt < 30) {
        #pragma unroll
        for (int r = 0; r < 4; ++r)
          gLs[quad*4 + r][nt*16 + cl] = acc[i][r];
      }
    }
    __syncthreads();   // gates visible
    #pragma unroll
    for (int rr = 0; rr < 2; ++rr) {
      const int row = prow + rr;
      if (act) {
        const float2 gi = *(const float2*)&gLs[row][d0      ];
        const float2 gf = *(const float2*)&gLs[row][d0 + 120];
        const float2 gg = *(const float2*)&gLs[row][d0 + 240];
        const float2 go = *(const float2*)&gLs[row][d0 + 360];
        float h2[2];
        #pragma unroll
        for (int k = 0; k < 2; ++k) {
          const float vi = k ? gi.y : gi.x, vf = k ? gf.y : gf.x;
          const float vg = k ? gg.y : gg.x, vo = k ? go.y : go.x;
          const float si = 1.f / (1.f + __expf(-vi));
          const float sf = 1.f / (1.f + __expf(-vf));
          const float tg = 1.f - 2.f / (__expf(2.f*vg) + 1.f);
          const float so = 1.f / (1.f + __expf(-vo));
          const float c  = sf * C[rr][k] + si * tg;
          C[rr][k] = c;
          const float tc = 1.f - 2.f / (__expf(2.f*c) + 1.f);
          h2[k] = so * tc;
        }
        *(u32*)&hLh[row][d0] = packh2(h2[0], h2[1]);
        *(u32*)&hb0[((size_t)t*BSZ + b0 + row)*KP + d0] = packh2(h2[0], h2[1]);
      } else {
        // lanes 60..63: zero hb0 pad cols 120..127 (2 per lane)
        *(u32*)&hb0[((size_t)t*BSZ + b0 + row)*KP + 120 + 2*(lane - 60)] = 0u;
      }
    }
  }
}

// ---------------- k_rec1: fused src-GEMM + LSTM + shuffle-LayerNorm ----------------
// gates = b1s + hb0[t]@Wih1^T + h1@Whh1^T (resident f16 frags). A0 frags
// prefetched from global 1 step ahead. Phase B wave-owns-2-rows; LN mean/var
// via __shfl_xor tree (no extra barriers). 2 barriers/step.
__global__ __launch_bounds__(512) void k_rec1(const float* __restrict__ Wih1,
                                              const float* __restrict__ Whh1,
                                              const float* __restrict__ b1s,
                                              const _Float16* __restrict__ hb0,
                                              const float* __restrict__ gamma,
                                              const float* __restrict__ beta,
                                              u16* __restrict__ h1n)
{
  __shared__ float gLs[TB][GP];                    // 30976 B
  __shared__ __align__(16) _Float16 hLh[TB][HP];   //  4352 B

  const int tid  = threadIdx.x;
  const int wave = tid >> 6, lane = tid & 63;
  const int cl   = lane & 15, quad = lane >> 4;
  const int b0   = blockIdx.x * TB;

  for (int i = tid; i < TB*HP; i += 512) (&hLh[0][0])[i] = (_Float16)0.f;

  v8h Bi[4][4], Bh[4][4];
  float bias[4];
  #pragma unroll
  for (int i = 0; i < 4; ++i) {
    const int nt = wave*4 + i;
    const bool vld = (nt < 30);
    const int n = vld ? nt*16 + cl : 0;
    bias[i] = vld ? b1s[n] : 0.f;
    #pragma unroll
    for (int kt = 0; kt < 4; ++kt) {
      const int k0 = kt*32 + quad*8;
      v8h fi = {0,0,0,0,0,0,0,0}, fh = {0,0,0,0,0,0,0,0};
      if (vld && k0 < DIM) {
        float4 q0 = *(const float4*)(Wih1 + n*DIM + k0);
        float4 q1 = *(const float4*)(Wih1 + n*DIM + k0 + 4);
        fi[0]=(_Float16)q0.x; fi[1]=(_Float16)q0.y; fi[2]=(_Float16)q0.z; fi[3]=(_Float16)q0.w;
        fi[4]=(_Float16)q1.x; fi[5]=(_Float16)q1.y; fi[6]=(_Float16)q1.z; fi[7]=(_Float16)q1.w;
        float4 p0 = *(const float4*)(Whh1 + n*DIM + k0);
        float4 p1 = *(const float4*)(Whh1 + n*DIM + k0 + 4);
        fh[0]=(_Float16)p0.x; fh[1]=(_Float16)p0.y; fh[2]=(_Float16)p0.z; fh[3]=(_Float16)p0.w;
        fh[4]=(_Float16)p1.x; fh[5]=(_Float16)p1.y; fh[6]=(_Float16)p1.z; fh[7]=(_Float16)p1.w;
      }
      Bi[i][kt] = fi;
      Bh[i][kt] = fh;
    }
  }

  // phase-B mapping
  const int prow = wave*2;
  const bool act = lane < 60;
  const int d0   = lane*2;
  float gmm[2] = {0.f, 0.f}, bta[2] = {0.f, 0.f};
  if (act) {
    gmm[0] = gamma[d0]; gmm[1] = gamma[d0+1];
    bta[0] = beta[d0];  bta[1] = beta[d0+1];
  }
  float C[2][2] = {{0.f,0.f},{0.f,0.f}};

  // A0 prefetch (t=0)
  v8h A0n[4];
  #pragma unroll
  for (int kt = 0; kt < 4; ++kt)
    A0n[kt] = *(const v8h*)&hb0[((size_t)0*BSZ + b0 + cl)*KP + kt*32 + quad*8];
  __syncthreads();

  for (int t = 0; t < SEQ; ++t) {
    v8h A0c[4], A1[4];
    #pragma unroll
    for (int kt = 0; kt < 4; ++kt) A0c[kt] = A0n[kt];
    #pragma unroll
    for (int kt = 0; kt < 4; ++kt)
      A1[kt] = *(const v8h*)&hLh[cl][kt*32 + quad*8];
    if (t + 1 < SEQ) {
      #pragma unroll
      for (int kt = 0; kt < 4; ++kt)
        A0n[kt] = *(const v8h*)&hb0[((size_t)(t+1)*BSZ + b0 + cl)*KP + kt*32 + quad*8];
    }
    v4f acc[4];
    #pragma unroll
    for (int i = 0; i < 4; ++i)
      acc[i] = (v4f){bias[i], bias[i], bias[i], bias[i]};
    #pragma unroll
    for (int i = 0; i < 4; ++i)
      if (wave*4 + i < 30) {
        #pragma unroll
        for (int kt = 0; kt < 4; ++kt) {
          acc[i] = __builtin_amdgcn_mfma_f32_16x16x32_f16(A0c[kt], Bi[i][kt], acc[i], 0, 0, 0);
          acc[i] = __builtin_amdgcn_mfma_f32_16x16x32_f16(A1[kt],  Bh[i][kt], acc[i], 0, 0, 0);
        }
      }
    #pragma unroll
    for (int i = 0; i < 4; ++i) {
      const int nt = wave*4 + i;
      if (nt < 30) {
        #pragma unroll
        for (int r = 0; r < 4; ++r)
          gLs[quad*4 + r][nt*16 + cl] = acc[i][r];
      }
    }
    __syncthreads();   // gates visible
    float h2[2][2] = {{0.f,0.f},{0.f,0.f}};
    float s1[2] = {0.f, 0.f}, s2[2] = {0.f, 0.f};
    #pragma unroll
    for (int rr = 0; rr < 2; ++rr) {
      const int row = prow + rr;
      if (act) {
        const float2 gi = *(const float2*)&gLs[row][d0      ];
        const float2 gf = *(const float2*)&gLs[row][d0 + 120];
        const float2 gg = *(const float2*)&gLs[row][d0 + 240];
        const float2 go = *(const float2*)&gLs[row][d0 + 360];
        #pragma unroll
        for (int k = 0; k < 2; ++k) {
          const float vi = k ? gi.y : gi.x, vf = k ? gf.y : gf.x;
          const float vg = k ? gg.y : gg.x, vo = k ? go.y : go.x;
          const float si = 1.f / (1.f + __expf(-vi));
          const float sf = 1.f / (1.f + __expf(-vf));
          const float tg = 1.f - 2.f / (__expf(2.f*vg) + 1.f);
          const float so = 1.f / (1.f + __expf(-vo));
          const float c  = sf * C[rr][k] + si * tg;
          C[rr][k] = c;
          const float tc = 1.f - 2.f / (__expf(2.f*c) + 1.f);
          const float h  = so * tc;
          h2[rr][k] = h;
          s1[rr] += h;
          s2[rr] = fmaf(h, h, s2[rr]);
        }
        *(u32*)&hLh[row][d0] = packh2(h2[rr][0], h2[rr][1]);
      }
    }
    // LN reduction across the wave (all 64 lanes participate; idle lanes add 0)
    #pragma unroll
    for (int m = 32; m >= 1; m >>= 1) {
      s1[0] += __shfl_xor(s1[0], m);
      s2[0] += __shfl_xor(s2[0], m);
      s1[1] += __shfl_xor(s1[1], m);
      s2[1] += __shfl_xor(s2[1], m);
    }
    #pragma unroll
    for (int rr = 0; rr < 2; ++rr) {
      const int row = prow + rr;
      const float mu = s1[rr] * (1.f/DIM);
      const float var = s2[rr] * (1.f/DIM) - mu*mu;
      const float rs = rsqrtf(var + 1e-5f);
      u16* dst = &h1n[((size_t)(b0 + row)*SEQ + t)*KP];
      if (act) {
        const float v0 = fmaf((h2[rr][0] - mu)*rs, gmm[0], bta[0]);
        const float v1 = fmaf((h2[rr][1] - mu)*rs, gmm[1], bta[1]);
        *(u32*)&dst[d0] = (u32)f2bf(v0) | ((u32)f2bf(v1) << 16);
      } else {
        *(u32*)&dst[120 + 2*(lane - 60)] = 0u;   // zero pad cols
      }
    }
    __syncthreads();   // hLh stable before next step's A1 reads
  }
}

// ---------------- k_head: MFMA GEMM logits = h1n @ embP^T (f32 out) ----------------
__global__ __launch_bounds__(256) void k_head(const u16* __restrict__ A,   // [M][128]
                                              const u16* __restrict__ Bp,  // [448][128]
                                              float* __restrict__ out)     // [M][433]
{
  const int wv = threadIdx.x >> 6, lane = threadIdx.x & 63;
  const int cl = lane & 15, quad = lane >> 4;
  const int mtb = (blockIdx.x*4 + wv)*4;
  v8bf a[4][4];
  #pragma unroll
  for (int i = 0; i < 4; ++i)
    #pragma unroll
    for (int kt = 0; kt < 4; ++kt)
      a[i][kt] = *(const v8bf*)&A[((size_t)(mtb+i)*16 + cl)*KP + kt*32 + quad*8];
  for (int nt = 0; nt < NPAD/16; ++nt) {
    const int n = nt*16 + cl;
    v8bf bfr[4];
    #pragma unroll
    for (int kt = 0; kt < 4; ++kt)
      bfr[kt] = *(const v8bf*)&Bp[(size_t)n*KP + kt*32 + quad*8];
    #pragma unroll
    for (int i = 0; i < 4; ++i) {
      v4f acc = {0.f, 0.f, 0.f, 0.f};
      #pragma unroll
      for (int kt = 0; kt < 4; ++kt)
        acc = __builtin_amdgcn_mfma_f32_16x16x32_bf16(a[i][kt], bfr[kt], acc, 0, 0, 0);
      if (n < VSZ) {
        #pragma unroll
        for (int r = 0; r < 4; ++r)
          out[(size_t)((mtb+i)*16 + quad*4 + r)*VSZ + n] = acc[r];
      }
    }
  }
}

// ---------------- launch ----------------
extern "C" void kernel_launch(void* const* d_in, const int* in_sizes, int n_in,
                              void* d_out, int out_size, void* d_ws, size_t ws_size,
                              hipStream_t stream)
{
  (void)in_sizes; (void)n_in; (void)out_size; (void)ws_size;
  const int*   x     = (const int*)d_in[0];
  const float* embed = (const float*)d_in[1];
  const float* Wih0  = (const float*)d_in[2];
  const float* Whh0  = (const float*)d_in[3];
  const float* bih0  = (const float*)d_in[4];
  const float* bhh0  = (const float*)d_in[5];
  const float* Wih1  = (const float*)d_in[6];
  const float* Whh1  = (const float*)d_in[7];
  const float* bih1  = (const float*)d_in[8];
  const float* bhh1  = (const float*)d_in[9];
  const float* gamma = (const float*)d_in[10];
  const float* beta  = (const float*)d_in[11];

  char* ws = (char*)d_ws;
  float*     EW   = (float*)(ws + EW_OFF);
  float*     b1s  = (float*)(ws + B1S_OFF);
  u16*       embP = (u16*)(ws + EMBP_OFF);
  _Float16*  hb0  = (_Float16*)(ws + HB0_OFF);
  u16*       h1n  = (u16*)(ws + H1N_OFF);

  k_ew   <<<VSZ, 512, 0, stream>>>(embed, Wih0, bih0, bhh0, EW);
  k_prep2<<<226, 256, 0, stream>>>(embed, bih1, bhh1, embP, b1s);
  k_rec0 <<<BSZ/TB, 512, 0, stream>>>(Whh0, EW, x, hb0);
  k_rec1 <<<BSZ/TB, 512, 0, stream>>>(Wih1, Whh1, b1s, hb0, gamma, beta, h1n);
  k_head <<<MTOT/256, 256, 0, stream>>>(h1n, embP, (float*)d_out);
}